// Round 1
// baseline (343.123 us; speedup 1.0000x reference)
//
#include <hip/hip_runtime.h>

#define RN    8192
#define LOGN  13
#define NSH   31          // shifts -15..15
#define BLK   512         // threads per block (8 waves)
#define EPT   16          // elements per thread = RN/BLK
#define EPSF  1e-8f

// Per-row fused kernel: stats + 31-lag circular correlation + packed complex
// FFT (pc + i*tc) + power-spectrum KL. One block per row, everything LDS-resident.
__global__ __launch_bounds__(BLK) void hybrid_row_kernel(
    const float* __restrict__ preds, const float* __restrict__ targets,
    float* __restrict__ ws, int nrows)
{
  __shared__ __align__(16) float zr[RN];   // pc, later FFT real
  __shared__ __align__(16) float zi[RN];   // tc, later FFT imag
  __shared__ float red[NSH * 8 + 16];      // wave-partial scratch

  const int row = blockIdx.x;
  const int tid = threadIdx.x;
  const int wv  = tid >> 6;
  const int ln  = tid & 63;
  const float* __restrict__ prow = preds   + (size_t)row * RN;
  const float* __restrict__ trow = targets + (size_t)row * RN;

  // ---- coalesced load (float4) + mean partials ----
  float sp = 0.f, st = 0.f;
  #pragma unroll
  for (int j = 0; j < EPT / 4; ++j) {
    int v = tid + BLK * j;                 // float4 index
    float4 p = ((const float4*)prow)[v];
    float4 t = ((const float4*)trow)[v];
    sp += (p.x + p.y) + (p.z + p.w);
    st += (t.x + t.y) + (t.z + t.w);
    ((float4*)zr)[v] = p;
    ((float4*)zi)[v] = t;
  }
  #pragma unroll
  for (int off = 32; off; off >>= 1) {
    sp += __shfl_down(sp, off);
    st += __shfl_down(st, off);
  }
  if (ln == 0) { red[wv] = sp; red[8 + wv] = st; }
  __syncthreads();                         // covers zr/zi writes + red
  float mean_p = 0.f, mean_t = 0.f;
  #pragma unroll
  for (int w = 0; w < 8; ++w) { mean_p += red[w]; mean_t += red[8 + w]; }
  mean_p *= (1.0f / RN);  mean_t *= (1.0f / RN);
  __syncthreads();                         // red free for reuse

  // ---- center in place, cache tc slice in regs, sum-of-squares ----
  float ssp = 0.f, sst = 0.f;
  float tcr[EPT];
  #pragma unroll
  for (int j = 0; j < EPT; ++j) {
    int i = tid + BLK * j;
    float a = zr[i] - mean_p;
    float b = zi[i] - mean_t;
    zr[i] = a;  zi[i] = b;
    tcr[j] = b;
    ssp += a * a;  sst += b * b;
  }
  #pragma unroll
  for (int off = 32; off; off >>= 1) {
    ssp += __shfl_down(ssp, off);
    sst += __shfl_down(sst, off);
  }
  if (ln == 0) { red[wv] = ssp; red[8 + wv] = sst; }
  __syncthreads();                         // covers centered zr/zi + red
  float dp = 0.f, dt = 0.f;
  #pragma unroll
  for (int w = 0; w < 8; ++w) { dp += red[w]; dt += red[8 + w]; }
  const float inv_denom = rsqrtf((dp + EPSF) * (dt + EPSF)); // 1/(std_p*std_t)
  __syncthreads();                         // red free for correlation writes

  // ---- 31-shift circular correlation: cov(s) = sum pc[(i-s)&8191]*tc[i] ----
  #pragma unroll 1
  for (int s = 0; s < NSH; ++s) {
    int sh = s - 15;
    float acc = 0.f;
    #pragma unroll
    for (int j = 0; j < EPT; ++j) {
      int i = tid + BLK * j;
      acc += zr[(i - sh) & (RN - 1)] * tcr[j];
    }
    #pragma unroll
    for (int off = 32; off; off >>= 1) acc += __shfl_down(acc, off);
    if (ln == 0) red[s * 8 + wv] = acc;
  }
  __syncthreads();
  if (tid < 64) {                          // wave 0: finish 31 sums, max, clamp
    float c = -3.4e38f;
    if (tid < NSH) {
      float a = 0.f;
      #pragma unroll
      for (int w = 0; w < 8; ++w) a += red[tid * 8 + w];
      c = a * inv_denom;
    }
    #pragma unroll
    for (int off = 32; off; off >>= 1) c = fmaxf(c, __shfl_down(c, off));
    if (tid == 0) ws[row] = fmaxf(c, -1.0f);
  }
  __syncthreads();

  // ---- in-place bit-reversal permutation (disjoint 2-cycles) ----
  #pragma unroll
  for (int j = 0; j < EPT; ++j) {
    int i = tid + BLK * j;
    int r = (int)(__brev((unsigned)i) >> (32 - LOGN));
    if (r > i) {
      float a = zr[i]; zr[i] = zr[r]; zr[r] = a;
      float b = zi[i]; zi[i] = zi[r]; zi[r] = b;
    }
  }
  __syncthreads();

  // ---- 13 radix-2 DIT stages, forward (sign -) ----
  #pragma unroll 1
  for (int s = 0; s < LOGN; ++s) {
    int m = 1 << s;
    float inv_m = 1.0f / (float)m;
    #pragma unroll
    for (int u = 0; u < EPT / 2; ++u) {
      int b  = tid + BLK * u;              // butterfly id 0..4095
      int j  = b & (m - 1);
      int i0 = ((b >> s) << (s + 1)) | j;
      int i1 = i0 + m;
      float ang = -3.14159265358979f * (float)j * inv_m;
      float sn, cs;
      __sincosf(ang, &sn, &cs);            // w = cs + i*sn = exp(-i*pi*j/m)
      float x1 = zr[i1], y1 = zi[i1];
      float tr = cs * x1 - sn * y1;
      float ti = cs * y1 + sn * x1;
      float x0 = zr[i0], y0 = zi[i0];
      zr[i0] = x0 + tr;  zi[i0] = y0 + ti;
      zr[i1] = x0 - tr;  zi[i1] = y0 - ti;
    }
    __syncthreads();
  }

  // ---- split packed FFT -> power spectra (bins 1..4096) + KL ----
  // P[k] = (Z[k]+conj(Z[N-k]))/2 ; T[k] = (Z[k]-conj(Z[N-k]))/(2i)
  float pwp[EPT / 2], pwt[EPT / 2];
  float Sp = 0.f, St = 0.f;
  #pragma unroll
  for (int u = 0; u < EPT / 2; ++u) {
    int k  = 1 + tid + BLK * u;            // 1..4096
    int k2 = RN - k;                       // 4096..8191 (reads only, no hazard)
    float a = zr[k],  b = zi[k];
    float c = zr[k2], d = zi[k2];
    float rp = a + c, ip = b - d;          // 2*P
    float rt = b + d, it = c - a;          // 2*T
    float pp = 0.25f * (rp * rp + ip * ip);
    float tt = 0.25f * (rt * rt + it * it);
    pwp[u] = pp;  pwt[u] = tt;
    Sp += pp;  St += tt;
  }
  #pragma unroll
  for (int off = 32; off; off >>= 1) {
    Sp += __shfl_down(Sp, off);
    St += __shfl_down(St, off);
  }
  if (ln == 0) { red[wv] = Sp; red[8 + wv] = St; }
  __syncthreads();
  float tsp = 0.f, tst = 0.f;
  #pragma unroll
  for (int w = 0; w < 8; ++w) { tsp += red[w]; tst += red[8 + w]; }
  const float inv_sp = 1.0f / (tsp + EPSF);
  const float inv_st = 1.0f / (tst + EPSF);
  float kl = 0.f;
  #pragma unroll
  for (int u = 0; u < EPT / 2; ++u) {
    float qp = pwp[u] * inv_sp;
    float qt = pwt[u] * inv_st;
    kl += qt * (logf(qt + EPSF) - logf(qp + EPSF));
  }
  __syncthreads();                         // red consumed before overwrite
  #pragma unroll
  for (int off = 32; off; off >>= 1) kl += __shfl_down(kl, off);
  if (ln == 0) red[wv] = kl;
  __syncthreads();
  if (tid == 0) {
    float a = 0.f;
    #pragma unroll
    for (int w = 0; w < 8; ++w) a += red[w];
    ws[nrows + row] = a;
  }
}

__global__ __launch_bounds__(256) void hybrid_final_kernel(
    const float* __restrict__ ws, float* __restrict__ out, int nrows)
{
  __shared__ float red[8];
  int tid = threadIdx.x;
  float sb = 0.f, sk = 0.f;
  for (int i = tid; i < nrows; i += 256) {
    sb += ws[i];
    sk += ws[nrows + i];
  }
  #pragma unroll
  for (int off = 32; off; off >>= 1) {
    sb += __shfl_down(sb, off);
    sk += __shfl_down(sk, off);
  }
  int wv = tid >> 6, ln = tid & 63;
  if (ln == 0) { red[wv] = sb; red[4 + wv] = sk; }
  __syncthreads();
  if (tid == 0) {
    float a = 0.f, b = 0.f;
    #pragma unroll
    for (int w = 0; w < 4; ++w) { a += red[w]; b += red[4 + w]; }
    float time_loss = 1.0f - a / (float)nrows;
    float freq_loss = b / (float)nrows;
    out[0] = 0.5f * time_loss + 0.5f * freq_loss;   // FREQ_WEIGHT = 0.5
  }
}

extern "C" void kernel_launch(void* const* d_in, const int* in_sizes, int n_in,
                              void* d_out, int out_size, void* d_ws, size_t ws_size,
                              hipStream_t stream) {
  const float* preds   = (const float*)d_in[0];
  const float* targets = (const float*)d_in[1];
  float* out = (float*)d_out;
  float* ws  = (float*)d_ws;   // [0..nrows): best_pearson, [nrows..2*nrows): kl
  int nrows = in_sizes[0] / RN;
  hipLaunchKernelGGL(hybrid_row_kernel, dim3(nrows), dim3(BLK), 0, stream,
                     preds, targets, ws, nrows);
  hipLaunchKernelGGL(hybrid_final_kernel, dim3(1), dim3(256), 0, stream,
                     ws, out, nrows);
}

// Round 2
// 194.693 us; speedup vs baseline: 1.7624x; 1.7624x over previous
//
#include <hip/hip_runtime.h>

#define RN    8192
#define NSH   31          // shifts -15..15
#define BLK   512         // threads per block (8 waves)
#define EPSF  1e-8f

// ---- LDS swizzle: XOR dword-index bits 2-4 with bits 7-9. Preserves b64/b128
// blocks (bits 0-1 untouched); spreads small-span FFT addresses across banks.
__device__ __forceinline__ int SWZ(int i)  { return i ^ (((i >> 7) & 7) << 2); }
__device__ __forceinline__ int SW4(int f)  { return f ^ (((f >> 5) & 7)); }   // float4-index view

// digit-reversed position of frequency k after DIF radices 8,8,8,16
__device__ __forceinline__ int PPOS(int k) {
  return ((k & 7) << 10) | (((k >> 3) & 7) << 7) | (((k >> 6) & 7) << 4) | (k >> 9);
}

// ---- 8-point DFT, fully in registers. yr/yi in natural order -> Y_q in slot q.
__device__ __forceinline__ void dft8(float yr[8], float yi[8]) {
  const float C = 0.7071067811865476f;
  float ar, ai;
  float u0r = yr[0] + yr[4], u0i = yi[0] + yi[4];
  float v0r = yr[0] - yr[4], v0i = yi[0] - yi[4];
  float u1r = yr[1] + yr[5], u1i = yi[1] + yi[5];
  ar = yr[1] - yr[5]; ai = yi[1] - yi[5];
  float v1r = C * (ar + ai), v1i = C * (ai - ar);          // * W8^1
  float u2r = yr[2] + yr[6], u2i = yi[2] + yi[6];
  ar = yr[2] - yr[6]; ai = yi[2] - yi[6];
  float v2r = ai, v2i = -ar;                               // * W8^2 = -i
  float u3r = yr[3] + yr[7], u3i = yi[3] + yi[7];
  ar = yr[3] - yr[7]; ai = yi[3] - yi[7];
  float v3r = C * (ai - ar), v3i = -C * (ar + ai);         // * W8^3
  // DFT4(u) -> Y0 Y2 Y4 Y6
  float t0r = u0r + u2r, t0i = u0i + u2i;
  float t1r = u1r + u3r, t1i = u1i + u3i;
  float t2r = u0r - u2r, t2i = u0i - u2i;
  float t3r = u1r - u3r, t3i = u1i - u3i;
  yr[0] = t0r + t1r; yi[0] = t0i + t1i;
  yr[4] = t0r - t1r; yi[4] = t0i - t1i;
  yr[2] = t2r + t3i; yi[2] = t2i - t3r;                    // t2 - i t3
  yr[6] = t2r - t3i; yi[6] = t2i + t3r;                    // t2 + i t3
  // DFT4(v) -> Y1 Y3 Y5 Y7
  t0r = v0r + v2r; t0i = v0i + v2i;
  t1r = v1r + v3r; t1i = v1i + v3i;
  t2r = v0r - v2r; t2i = v0i - v2i;
  t3r = v1r - v3r; t3i = v1i - v3i;
  yr[1] = t0r + t1r; yi[1] = t0i + t1i;
  yr[5] = t0r - t1r; yi[5] = t0i - t1i;
  yr[3] = t2r + t3i; yi[3] = t2i - t3r;
  yr[7] = t2r - t3i; yi[7] = t2i + t3r;
}

// 16-point DFT in registers (even/odd split into two dft8 + const twiddles)
__device__ __forceinline__ void dft16(float zr[16], float zi[16]) {
  float er[8], ei[8], odr[8], odi[8];
  #pragma unroll
  for (int m = 0; m < 8; ++m) {
    er[m] = zr[2*m];   ei[m] = zi[2*m];
    odr[m] = zr[2*m+1]; odi[m] = zi[2*m+1];
  }
  dft8(er, ei); dft8(odr, odi);
  const float c1 = 0.9238795325112867f, s1 = 0.3826834323650898f;
  const float C  = 0.7071067811865476f;
  const float WR[8] = {1.f,  c1,  C,  s1, 0.f, -s1, -C, -c1};
  const float WI[8] = {0.f, -s1, -C, -c1, -1.f, -c1, -C, -s1};
  #pragma unroll
  for (int q = 0; q < 8; ++q) {
    float tr = odr[q]*WR[q] - odi[q]*WI[q];
    float ti = odr[q]*WI[q] + odi[q]*WR[q];
    zr[q]     = er[q] + tr; zi[q]     = ei[q] + ti;
    zr[q + 8] = er[q] - tr; zi[q + 8] = ei[q] - ti;
  }
}

// one DIF radix-8 pass, span L = 8*S; thread handles butterflies j=2t, 2t+1
// (adjacent -> all LDS access is float2). In-place; each butterfly owns its 8 slots.
template<int LOG2S>
__device__ __forceinline__ void fft_pass8(float* zr, float* zi, int t) {
  const int S = 1 << LOG2S;
  const int g = 2 * t;
  const int j = g & (S - 1);
  const int base = ((g >> LOG2S) << (LOG2S + 3)) + j;
  float ar[8], ai[8], br[8], bi[8];
  #pragma unroll
  for (int m = 0; m < 8; ++m) {
    int i = SWZ(base + m * S);
    float2 xr = *(const float2*)&zr[i];
    float2 xim = *(const float2*)&zi[i];
    ar[m] = xr.x; br[m] = xr.y; ai[m] = xim.x; bi[m] = xim.y;
  }
  dft8(ar, ai); dft8(br, bi);
  const float angu = -3.14159265358979323846f / (4.0f * (float)S); // -2pi/(8S)
  float s0, c0, s1_, c1;
  __sincosf(angu * (float)j, &s0, &c0);
  __sincosf(angu * (float)(j + 1), &s1_, &c1);
  float war = c0, wai = s0, wbr = c1, wbi = s1_;   // W^1 for each butterfly
  #pragma unroll
  for (int q = 1; q < 8; ++q) {
    float tr = ar[q]*war - ai[q]*wai; ai[q] = ar[q]*wai + ai[q]*war; ar[q] = tr;
    float ur = br[q]*wbr - bi[q]*wbi; bi[q] = br[q]*wbi + bi[q]*wbr; br[q] = ur;
    if (q < 7) {
      float nr = war*c0 - wai*s0; wai = war*s0 + wai*c0; war = nr;
      float mr = wbr*c1 - wbi*s1_; wbi = wbr*s1_ + wbi*c1; wbr = mr;
    }
  }
  #pragma unroll
  for (int m = 0; m < 8; ++m) {
    int i = SWZ(base + m * S);
    *(float2*)&zr[i] = make_float2(ar[m], br[m]);
    *(float2*)&zi[i] = make_float2(ai[m], bi[m]);
  }
}

__global__ __launch_bounds__(BLK, 4) void hybrid_row_kernel(
    const float* __restrict__ preds, const float* __restrict__ targets,
    float* __restrict__ ws, int nrows)
{
  __shared__ __align__(16) float zr[RN];   // pc, then FFT real (swizzled layout)
  __shared__ __align__(16) float zi[RN];   // tc, then FFT imag
  __shared__ __align__(16) float sc[2176]; // part[31] stride-68 + red/covf tail

  float* red  = &sc[31 * 68];        // 32 slots: [0..16) means, [16..32) var / Sp,St / kl
  float* covf = &sc[31 * 68 + 32];   // 31 slots

  const int row = blockIdx.x;
  const int tid = threadIdx.x;
  const int wv  = tid >> 6;
  const int ln  = tid & 63;
  const float* __restrict__ prow = preds   + (size_t)row * RN;
  const float* __restrict__ trow = targets + (size_t)row * RN;

  // ---- phase 1: global load (strided f4, coalesced), keep in regs, mean partials
  float pr[16], tw[16];
  float sp = 0.f, st = 0.f;
  #pragma unroll
  for (int c = 0; c < 4; ++c) {
    int f = tid + 512 * c;
    float4 p = ((const float4*)prow)[f];
    float4 q = ((const float4*)trow)[f];
    pr[4*c+0] = p.x; pr[4*c+1] = p.y; pr[4*c+2] = p.z; pr[4*c+3] = p.w;
    tw[4*c+0] = q.x; tw[4*c+1] = q.y; tw[4*c+2] = q.z; tw[4*c+3] = q.w;
    sp += (p.x + p.y) + (p.z + p.w);
    st += (q.x + q.y) + (q.z + q.w);
  }
  #pragma unroll
  for (int off = 32; off; off >>= 1) { sp += __shfl_down(sp, off); st += __shfl_down(st, off); }
  if (ln == 0) { red[wv] = sp; red[8 + wv] = st; }
  __syncthreads();                                   // b1
  float mean_p = 0.f, mean_t = 0.f;
  #pragma unroll
  for (int w = 0; w < 8; ++w) { mean_p += red[w]; mean_t += red[8 + w]; }
  mean_p *= (1.0f / RN); mean_t *= (1.0f / RN);

  // ---- phase 2: center in regs, single LDS write (swizzled), sumsq partials
  float ssp = 0.f, sst = 0.f;
  #pragma unroll
  for (int c = 0; c < 4; ++c) {
    int f = tid + 512 * c;
    float a0 = pr[4*c+0] - mean_p, a1 = pr[4*c+1] - mean_p;
    float a2 = pr[4*c+2] - mean_p, a3 = pr[4*c+3] - mean_p;
    float b0 = tw[4*c+0] - mean_t, b1 = tw[4*c+1] - mean_t;
    float b2 = tw[4*c+2] - mean_t, b3 = tw[4*c+3] - mean_t;
    ((float4*)zr)[SW4(f)] = make_float4(a0, a1, a2, a3);
    ((float4*)zi)[SW4(f)] = make_float4(b0, b1, b2, b3);
    ssp += (a0*a0 + a1*a1) + (a2*a2 + a3*a3);
    sst += (b0*b0 + b1*b1) + (b2*b2 + b3*b3);
  }
  #pragma unroll
  for (int off = 32; off; off >>= 1) { ssp += __shfl_down(ssp, off); sst += __shfl_down(sst, off); }
  if (ln == 0) { red[16 + wv] = ssp; red[24 + wv] = sst; }
  __syncthreads();                                   // b2
  float dp = 0.f, dt = 0.f;
  #pragma unroll
  for (int w = 0; w < 8; ++w) { dp += red[16 + w]; dt += red[24 + w]; }
  const float inv_denom = rsqrtf((dp + EPSF) * (dt + EPSF));

  // ---- phase 3: 31-shift circular correlation, contiguous ownership [16t,16t+16)
  float tq[16];
  #pragma unroll
  for (int c = 0; c < 4; ++c) {
    float4 v = ((const float4*)zi)[SW4(4 * tid + c)];
    tq[4*c+0] = v.x; tq[4*c+1] = v.y; tq[4*c+2] = v.z; tq[4*c+3] = v.w;
  }
  // group A: shifts s=0..15 -> window y in [16,47), local idx = 15-s+e
  {
    float wa[32];
    #pragma unroll
    for (int c = 0; c < 8; ++c) {
      int f = (4 * tid - 4 + (c + 4)) & 2047;
      float4 v = ((const float4*)zr)[SW4(f)];
      wa[4*c+0] = v.x; wa[4*c+1] = v.y; wa[4*c+2] = v.z; wa[4*c+3] = v.w;
    }
    float acc[16];
    #pragma unroll
    for (int s = 0; s < 16; ++s) acc[s] = 0.f;
    #pragma unroll
    for (int e = 0; e < 16; ++e)
      #pragma unroll
      for (int s = 0; s < 16; ++s)
        acc[s] += wa[15 - s + e] * tq[e];
    #pragma unroll
    for (int s = 0; s < 16; ++s) {
      float a = acc[s];
      a += __shfl_down(a, 4); a += __shfl_down(a, 2); a += __shfl_down(a, 1);
      if ((tid & 7) == 0) sc[s * 68 + (tid >> 3)] = a;
    }
  }
  // group B: shifts s=16..30 -> window y in [0,31), local idx = 15-s2+e
  {
    float wb[32];
    #pragma unroll
    for (int c = 0; c < 8; ++c) {
      int f = (4 * tid - 4 + c) & 2047;
      float4 v = ((const float4*)zr)[SW4(f)];
      wb[4*c+0] = v.x; wb[4*c+1] = v.y; wb[4*c+2] = v.z; wb[4*c+3] = v.w;
    }
    float acc[15];
    #pragma unroll
    for (int s = 0; s < 15; ++s) acc[s] = 0.f;
    #pragma unroll
    for (int e = 0; e < 16; ++e)
      #pragma unroll
      for (int s = 0; s < 15; ++s)
        acc[s] += wb[15 - s + e] * tq[e];
    #pragma unroll
    for (int s = 0; s < 15; ++s) {
      float a = acc[s];
      a += __shfl_down(a, 4); a += __shfl_down(a, 2); a += __shfl_down(a, 1);
      if ((tid & 7) == 0) sc[(16 + s) * 68 + (tid >> 3)] = a;
    }
  }
  __syncthreads();                                   // b3
  // finish covariances (31 lanes) while everyone starts FFT pass 1
  if (tid < 31) {
    float a = 0.f;
    #pragma unroll
    for (int c = 0; c < 16; ++c) {
      float4 v = ((const float4*)sc)[tid * 17 + c];
      a += (v.x + v.y) + (v.z + v.w);
    }
    covf[tid] = a * inv_denom;
  }

  // ---- phase 4-7: FFT of z = pc + i*tc, DIF radices 8,8,8,16 (output digit-reversed)
  fft_pass8<10>(zr, zi, tid);                        // span 8192
  __syncthreads();                                   // b4
  if (tid < 64) {                                    // wave 0: best pearson
    float c = (tid < 31) ? covf[tid] : -3.4e38f;
    #pragma unroll
    for (int off = 32; off; off >>= 1) c = fmaxf(c, __shfl_down(c, off));
    if (tid == 0) ws[row] = fmaxf(c, -1.0f);
  }
  fft_pass8<7>(zr, zi, tid);                         // span 1024
  __syncthreads();                                   // b5
  fft_pass8<4>(zr, zi, tid);                         // span 128
  __syncthreads();                                   // b6
  {                                                  // span 16: radix-16, j=0, no twiddles
    float xr[16], xim[16];
    #pragma unroll
    for (int c = 0; c < 4; ++c) {
      float4 a = ((const float4*)zr)[SW4(4 * tid + c)];
      float4 b = ((const float4*)zi)[SW4(4 * tid + c)];
      xr[4*c+0] = a.x; xr[4*c+1] = a.y; xr[4*c+2] = a.z; xr[4*c+3] = a.w;
      xim[4*c+0] = b.x; xim[4*c+1] = b.y; xim[4*c+2] = b.z; xim[4*c+3] = b.w;
    }
    __syncthreads();                                 // b7 (all reads done before writes)
    dft16(xr, xim);
    #pragma unroll
    for (int c = 0; c < 4; ++c) {
      ((float4*)zr)[SW4(4 * tid + c)] = make_float4(xr[4*c], xr[4*c+1], xr[4*c+2], xr[4*c+3]);
      ((float4*)zi)[SW4(4 * tid + c)] = make_float4(xim[4*c], xim[4*c+1], xim[4*c+2], xim[4*c+3]);
    }
  }
  __syncthreads();                                   // b8

  // ---- phase 8: packed-FFT split -> power spectra bins 1..4096 + KL
  // bank-friendly bin mapping: j = q4(l&7)<<9 | q3((l>>3)&7)<<6 | u<<3 | (tid>>6)
  const int l = tid & 63, wq = tid >> 6;
  float ppv[8], ttv[8];
  float Sp = 0.f, St = 0.f;
  #pragma unroll
  for (int u = 0; u < 8; ++u) {
    int j = ((l & 7) << 9) | (((l >> 3) & 7) << 6) | (u << 3) | wq;
    int k = j ? j : 4096;                            // j=0 slot handles Nyquist bin
    int p1 = PPOS(k), p2 = PPOS(8192 - k);
    float a = zr[SWZ(p1)], b = zi[SWZ(p1)];
    float c = zr[SWZ(p2)], d = zi[SWZ(p2)];
    float rp = a + c, ip = b - d;                    // 2*P[k]
    float rt = b + d, it = c - a;                    // 2*T[k]
    float pp = 0.25f * (rp*rp + ip*ip);
    float tt = 0.25f * (rt*rt + it*it);
    ppv[u] = pp; ttv[u] = tt; Sp += pp; St += tt;
  }
  #pragma unroll
  for (int off = 32; off; off >>= 1) { Sp += __shfl_down(Sp, off); St += __shfl_down(St, off); }
  if (ln == 0) { red[wv] = Sp; red[8 + wv] = St; }
  __syncthreads();                                   // b9
  float tsp = 0.f, tst = 0.f;
  #pragma unroll
  for (int w = 0; w < 8; ++w) { tsp += red[w]; tst += red[8 + w]; }
  const float inv_sp = 1.0f / (tsp + EPSF);
  const float inv_st = 1.0f / (tst + EPSF);
  float kl = 0.f;
  #pragma unroll
  for (int u = 0; u < 8; ++u) {
    float qp = ppv[u] * inv_sp;
    float qt = ttv[u] * inv_st;
    kl += qt * (__log2f(qt + EPSF) - __log2f(qp + EPSF));
  }
  kl *= 0.6931471805599453f;
  #pragma unroll
  for (int off = 32; off; off >>= 1) kl += __shfl_down(kl, off);
  if (ln == 0) red[16 + wv] = kl;
  __syncthreads();                                   // b10
  if (tid == 0) {
    float a = 0.f;
    #pragma unroll
    for (int w = 0; w < 8; ++w) a += red[16 + w];
    ws[nrows + row] = a;
  }
}

__global__ __launch_bounds__(256) void hybrid_final_kernel(
    const float* __restrict__ ws, float* __restrict__ out, int nrows)
{
  __shared__ float red[8];
  int tid = threadIdx.x;
  float sb = 0.f, sk = 0.f;
  for (int i = tid; i < nrows; i += 256) {
    sb += ws[i];
    sk += ws[nrows + i];
  }
  #pragma unroll
  for (int off = 32; off; off >>= 1) {
    sb += __shfl_down(sb, off);
    sk += __shfl_down(sk, off);
  }
  int wv = tid >> 6, ln = tid & 63;
  if (ln == 0) { red[wv] = sb; red[4 + wv] = sk; }
  __syncthreads();
  if (tid == 0) {
    float a = 0.f, b = 0.f;
    #pragma unroll
    for (int w = 0; w < 4; ++w) { a += red[w]; b += red[4 + w]; }
    float time_loss = 1.0f - a / (float)nrows;
    float freq_loss = b / (float)nrows;
    out[0] = 0.5f * time_loss + 0.5f * freq_loss;   // FREQ_WEIGHT = 0.5
  }
}

extern "C" void kernel_launch(void* const* d_in, const int* in_sizes, int n_in,
                              void* d_out, int out_size, void* d_ws, size_t ws_size,
                              hipStream_t stream) {
  const float* preds   = (const float*)d_in[0];
  const float* targets = (const float*)d_in[1];
  float* out = (float*)d_out;
  float* ws  = (float*)d_ws;   // [0..nrows): best_pearson, [nrows..2*nrows): kl
  int nrows = in_sizes[0] / RN;
  hipLaunchKernelGGL(hybrid_row_kernel, dim3(nrows), dim3(BLK), 0, stream,
                     preds, targets, ws, nrows);
  hipLaunchKernelGGL(hybrid_final_kernel, dim3(1), dim3(256), 0, stream,
                     ws, out, nrows);
}